// Round 9
// baseline (542.113 us; speedup 1.0000x reference)
//
#include <hip/hip_runtime.h>
#include <hip/hip_bf16.h>

#define Ndim 4096
#define Edim 8192
#define Fdim 256
#define Bdim 16
#define EB (Edim * 2)      // bf16 row bytes = 16384
#define NT (Edim / 64)     // 128 K-tiles of BK=64

typedef __attribute__((ext_vector_type(8))) short bf16x8;
typedef __attribute__((ext_vector_type(4))) float f32x4;

__device__ __forceinline__ unsigned short f2bf(float f) {
  unsigned int u = __float_as_uint(f);
  u += 0x7fffu + ((u >> 16) & 1u);   // round-to-nearest-even
  return (unsigned short)(u >> 16);
}

__device__ __forceinline__ void gload_lds16(const void* g, void* l) {
  __builtin_amdgcn_global_load_lds(
      (const __attribute__((address_space(1))) unsigned int*)g,
      (__attribute__((address_space(3))) unsigned int*)l, 16, 0, 0);
}

// stage one 128x64 half-matrix: 512 threads x 2 loads x 16B
__device__ __forceinline__ void stage_half(const char* g, char* d) {
  gload_lds16(g, d);
  gload_lds16(g + (size_t)64 * EB, d + 8192);
}

// swizzled LDS fragment read: logical (row r, 16B col block kk*64+khi)
#define RD(base, r, kk) \
  (*(const bf16x8*)((base) + (r) * 128 + ((((kk) * 64) + khi) ^ (((r) & 7) << 4))))

#define SGB(mask, n) __builtin_amdgcn_sched_group_barrier((mask), (n), 0)

// ---------------- pass 1a: m_bf16 = bf16(w*inci + b) ----------------
__global__ void convert_m(const float* __restrict__ w, const float* __restrict__ inc,
                          const float* __restrict__ bb, unsigned short* __restrict__ m) {
  size_t i = ((size_t)blockIdx.x * 256 + threadIdx.x) * 4;
  float4 wv = *(const float4*)(w + i);
  float4 iv = *(const float4*)(inc + i);
  float4 bv = *(const float4*)(bb + i);
  ushort4 o;
  o.x = f2bf(fmaf(wv.x, iv.x, bv.x));
  o.y = f2bf(fmaf(wv.y, iv.y, bv.y));
  o.z = f2bf(fmaf(wv.z, iv.z, bv.z));
  o.w = f2bf(fmaf(wv.w, iv.w, bv.w));
  *(ushort4*)(m + i) = o;
}

// ---------------- pass 1b: xT[b][f][e] = bf16(x[b][e][f]) ----------------
__global__ void transpose_x(const float* __restrict__ x, unsigned short* __restrict__ xT) {
  __shared__ unsigned short tile[64][66];
  int e0 = blockIdx.x * 64, f0 = blockIdx.y * 64, b = blockIdx.z;
  const float* xb = x + (size_t)b * Edim * Fdim;
  unsigned short* xTb = xT + (size_t)b * Fdim * Edim;
  int t = threadIdx.x;
  int fl = t & 63, rq = t >> 6;
#pragma unroll
  for (int i = 0; i < 16; i++) {
    int el = rq * 16 + i;
    float v = xb[(size_t)(e0 + el) * Fdim + f0 + fl];
    tile[el][fl] = f2bf(v);
  }
  __syncthreads();
  int ep = (t & 31) * 2;
  int fr0 = t >> 5;
#pragma unroll
  for (int j = 0; j < 8; j++) {
    int fr = fr0 + j * 8;
    unsigned int pk = (unsigned int)tile[ep][fr] | ((unsigned int)tile[ep + 1][fr] << 16);
    *(unsigned int*)&xTb[(size_t)(f0 + fr) * Edim + e0 + ep] = pk;
  }
}

// -------- one K-tile = 4 phases; tail reads INTERLEAVED into MFMA via SGB ----
// P1: stage1; bar; lgkm0; SB0; { MFMA Q00 x16 || read bHi x4 }   (SGB 4x{4,1})
// P2: stage2; bar; lgkm0; SB0; { MFMA Q01 x16 || read aHi x8 }   (SGB 8x{2,1})
// P3: stage3; bar; lgkm0; SB0; MFMA Q10 x16; vmcnt(2); bar
// P4: stage4; bar; lgkm0; SB0; { MFMA Q11 x16 || read next aLo+bLo x12 } (4x{4,3})
// vmcnt(2)@P3 proves tile t+1's A and B fully landed, so P4's reads may
// target the other buffer. Never drains to 0 mid-loop.
// MODE: 2 steady; 1 tile NT-2 (S1,S2 only, vmcnt(0)); 0 last (no stage/tail).
template <int MODE>
__device__ __forceinline__ void ktile(
    const char* lA, const char* lB, const char* lAn, const char* lBn,
    char* d1, const char* g1, char* d2, const char* g2,
    char* d3, const char* g3, char* d4, const char* g4,
    int lane, int wr, int wc,
    bf16x8 (&aCur)[8], bf16x8 (&bLoC)[4], f32x4 acc[8][4]) {
  const int l15 = lane & 15;
  const int khi = (lane >> 4) << 4;
  bf16x8 bHi[4], aHi[8];

  // ---- P1 ----
  if constexpr (MODE >= 1) stage_half(g1, d1);
  __builtin_amdgcn_s_barrier();
  asm volatile("s_waitcnt lgkmcnt(0)" ::: "memory");
  __builtin_amdgcn_sched_barrier(0);
  __builtin_amdgcn_s_setprio(1);
#pragma unroll
  for (int m = 0; m < 4; ++m)
#pragma unroll
    for (int n = 0; n < 2; ++n)
#pragma unroll
      for (int kk = 0; kk < 2; ++kk)
        acc[m][n] = __builtin_amdgcn_mfma_f32_16x16x32_bf16(aCur[m * 2 + kk], bLoC[n * 2 + kk],
                                                            acc[m][n], 0, 0, 0);
#pragma unroll
  for (int n = 0; n < 2; ++n)
#pragma unroll
    for (int kk = 0; kk < 2; ++kk)
      bHi[n * 2 + kk] = RD(lB, wc * 64 + (n + 2) * 16 + l15, kk);
#pragma unroll
  for (int q = 0; q < 4; ++q) { SGB(0x8, 4); SGB(0x100, 1); }
  __builtin_amdgcn_s_setprio(0);
  __builtin_amdgcn_s_barrier();

  // ---- P2 ----
  if constexpr (MODE >= 1) stage_half(g2, d2);
  __builtin_amdgcn_s_barrier();
  asm volatile("s_waitcnt lgkmcnt(0)" ::: "memory");
  __builtin_amdgcn_sched_barrier(0);
  __builtin_amdgcn_s_setprio(1);
#pragma unroll
  for (int m = 0; m < 4; ++m)
#pragma unroll
    for (int n = 0; n < 2; ++n)
#pragma unroll
      for (int kk = 0; kk < 2; ++kk)
        acc[m][n + 2] = __builtin_amdgcn_mfma_f32_16x16x32_bf16(aCur[m * 2 + kk], bHi[n * 2 + kk],
                                                                acc[m][n + 2], 0, 0, 0);
#pragma unroll
  for (int m = 0; m < 4; ++m)
#pragma unroll
    for (int kk = 0; kk < 2; ++kk)
      aHi[m * 2 + kk] = RD(lA, wr * 128 + 64 + m * 16 + l15, kk);
#pragma unroll
  for (int q = 0; q < 8; ++q) { SGB(0x8, 2); SGB(0x100, 1); }
  __builtin_amdgcn_s_setprio(0);
  __builtin_amdgcn_s_barrier();

  // ---- P3 ----
  if constexpr (MODE == 2) stage_half(g3, d3);
  __builtin_amdgcn_s_barrier();
  asm volatile("s_waitcnt lgkmcnt(0)" ::: "memory");
  __builtin_amdgcn_sched_barrier(0);
  __builtin_amdgcn_s_setprio(1);
#pragma unroll
  for (int m = 0; m < 4; ++m)
#pragma unroll
    for (int n = 0; n < 2; ++n)
#pragma unroll
      for (int kk = 0; kk < 2; ++kk)
        acc[m + 4][n] = __builtin_amdgcn_mfma_f32_16x16x32_bf16(aHi[m * 2 + kk], bLoC[n * 2 + kk],
                                                                acc[m + 4][n], 0, 0, 0);
  __builtin_amdgcn_s_setprio(0);
  if constexpr (MODE == 2) asm volatile("s_waitcnt vmcnt(2)" ::: "memory");
  if constexpr (MODE == 1) asm volatile("s_waitcnt vmcnt(0)" ::: "memory");
  __builtin_amdgcn_s_barrier();

  // ---- P4 ----
  if constexpr (MODE == 2) stage_half(g4, d4);
  __builtin_amdgcn_s_barrier();
  asm volatile("s_waitcnt lgkmcnt(0)" ::: "memory");
  __builtin_amdgcn_sched_barrier(0);
  __builtin_amdgcn_s_setprio(1);
#pragma unroll
  for (int m = 0; m < 4; ++m)
#pragma unroll
    for (int n = 0; n < 2; ++n)
#pragma unroll
      for (int kk = 0; kk < 2; ++kk)
        acc[m + 4][n + 2] = __builtin_amdgcn_mfma_f32_16x16x32_bf16(aHi[m * 2 + kk], bHi[n * 2 + kk],
                                                                    acc[m + 4][n + 2], 0, 0, 0);
  if constexpr (MODE >= 1) {
#pragma unroll
    for (int m = 0; m < 4; ++m)
#pragma unroll
      for (int kk = 0; kk < 2; ++kk)
        aCur[m * 2 + kk] = RD(lAn, wr * 128 + m * 16 + l15, kk);
#pragma unroll
    for (int n = 0; n < 2; ++n)
#pragma unroll
      for (int kk = 0; kk < 2; ++kk)
        bLoC[n * 2 + kk] = RD(lBn, wc * 64 + n * 16 + l15, kk);
#pragma unroll
    for (int q = 0; q < 4; ++q) { SGB(0x8, 4); SGB(0x100, 3); }
  }
  __builtin_amdgcn_s_setprio(0);
  __builtin_amdgcn_s_barrier();
}

__global__ __launch_bounds__(512, 2) void gemm8(
    const unsigned short* __restrict__ A,   // [Ndim][Edim] bf16
    const unsigned short* __restrict__ Bt,  // [Bdim][Fdim][Edim] bf16
    float* __restrict__ C) {                // [Bdim][Ndim][Fdim] f32
  // LDS: buf0.A=0 (h1 +16384) buf0.B.h0=32768 buf0.B.h1=49152
  //      buf1.A=65536 (h1 +16384) buf1.B.h0=98304 buf1.B.h1=114688
  __shared__ __align__(16) char smem[131072];

  const int bid = blockIdx.x;
  const int lid = ((bid & 7) << 5) | (bid >> 3);  // XCD-contiguous (256 % 8 == 0)
  const int mt = lid >> 4;   // node tile 0..15
  const int bb = lid & 15;   // batch

  const int tid = threadIdx.x;
  const int lane = tid & 63;
  const int w = tid >> 6;
  const int wr = w >> 2;     // 0..1
  const int wc = w & 3;      // 0..3
  const int l15 = lane & 15;
  const int khi = (lane >> 4) << 4;

  const int r0 = tid >> 3;                         // staging row 0..63
  const int c0 = ((tid & 7) ^ (r0 & 7)) << 4;      // pre-swizzled 16B source column

  const char* Ag = (const char*)A + (size_t)(mt * 256) * EB + (size_t)r0 * EB + c0;
  const char* Bg = (const char*)Bt + (size_t)(bb * 256) * EB + (size_t)r0 * EB + c0;
  char* dst = smem + tid * 16;

  f32x4 acc[8][4];
#pragma unroll
  for (int m = 0; m < 8; ++m)
#pragma unroll
    for (int n = 0; n < 4; ++n) acc[m][n] = (f32x4){0.f, 0.f, 0.f, 0.f};

  const size_t HEB = (size_t)128 * EB;  // half-tile row offset in bytes

  // prologue: t0 full -> buf0, t1.B -> buf1.B (12 loads); wait t0 (vmcnt(4))
  stage_half(Ag, dst);
  stage_half(Ag + HEB, dst + 16384);
  stage_half(Bg, dst + 32768);
  stage_half(Bg + HEB, dst + 49152);
  stage_half(Bg + 128, dst + 98304);
  stage_half(Bg + 128 + HEB, dst + 114688);
  asm volatile("s_waitcnt vmcnt(4)" ::: "memory");
  __builtin_amdgcn_s_barrier();

  // pre-read t0's aLo + bLo (the carried P1 inputs)
  bf16x8 aCur[8];
  bf16x8 bLoC[4];
#pragma unroll
  for (int m = 0; m < 4; ++m)
#pragma unroll
    for (int kk = 0; kk < 2; ++kk)
      aCur[m * 2 + kk] = RD((const char*)smem, wr * 128 + m * 16 + l15, kk);
#pragma unroll
  for (int n = 0; n < 2; ++n)
#pragma unroll
    for (int kk = 0; kk < 2; ++kk)
      bLoC[n * 2 + kk] = RD((const char*)smem + 32768, wc * 64 + n * 16 + l15, kk);

  for (int i = 0; i < NT / 2 - 1; ++i) {
    const size_t t1b = (size_t)(2 * i + 1) * 128;
    const size_t t2b = (size_t)(2 * i + 2) * 128;
    const size_t t3b = (size_t)(2 * i + 3) * 128;
    // K-tile 2i on buf0; stages: (2i+1).A -> buf1.A, (2i+2).B -> buf0.B
    ktile<2>(smem, smem + 32768, smem + 65536, smem + 98304,
             dst + 65536, Ag + t1b,
             dst + 81920, Ag + t1b + HEB,
             dst + 32768, Bg + t2b,
             dst + 49152, Bg + t2b + HEB,
             lane, wr, wc, aCur, bLoC, acc);
    // K-tile 2i+1 on buf1; stages: (2i+2).A -> buf0.A, (2i+3).B -> buf1.B
    ktile<2>(smem + 65536, smem + 98304, smem, smem + 32768,
             dst, Ag + t2b,
             dst + 16384, Ag + t2b + HEB,
             dst + 98304, Bg + t3b,
             dst + 114688, Bg + t3b + HEB,
             lane, wr, wc, aCur, bLoC, acc);
  }
  // tail: tile NT-2 (buf0) stages (NT-1).A, vmcnt(0)@P3; tile NT-1 (buf1) bare
  {
    const size_t tlb = (size_t)(NT - 1) * 128;
    ktile<1>(smem, smem + 32768, smem + 65536, smem + 98304,
             dst + 65536, Ag + tlb,
             dst + 81920, Ag + tlb + HEB,
             nullptr, nullptr, nullptr, nullptr,
             lane, wr, wc, aCur, bLoC, acc);
    ktile<0>(smem + 65536, smem + 98304, nullptr, nullptr,
             nullptr, nullptr, nullptr, nullptr,
             nullptr, nullptr, nullptr, nullptr,
             lane, wr, wc, aCur, bLoC, acc);
  }

  float* Cb = C + (size_t)bb * (Ndim * Fdim) + (size_t)(mt * 256) * Fdim;
#pragma unroll
  for (int m = 0; m < 8; ++m) {
    int row0 = wr * 128 + m * 16 + ((lane >> 4) << 2);
#pragma unroll
    for (int n = 0; n < 4; ++n) {
      int col = wc * 64 + n * 16 + (lane & 15);
#pragma unroll
      for (int j = 0; j < 4; ++j)
        Cb[(size_t)(row0 + j) * Fdim + col] = acc[m][n][j];
    }
  }
}

// ---------------- fallback (ws too small): slow but correct fp32 ----------------
__global__ void naive_kernel(const float* __restrict__ x, const float* __restrict__ inci,
                             const float* __restrict__ w, const float* __restrict__ b,
                             float* __restrict__ out) {
  int n = blockIdx.x & (Ndim - 1);
  int bb = blockIdx.x >> 12;
  int f = threadIdx.x;
  const float* xb = x + (size_t)bb * Edim * Fdim;
  const size_t nE = (size_t)n * Edim;
  float acc = 0.f;
  for (int e = 0; e < Edim; e++) {
    float m = fmaf(w[nE + e], inci[nE + e], b[nE + e]);
    acc = fmaf(m, xb[(size_t)e * Fdim + f], acc);
  }
  out[(size_t)bb * Ndim * Fdim + (size_t)n * Fdim + f] = acc;
}

extern "C" void kernel_launch(void* const* d_in, const int* in_sizes, int n_in,
                              void* d_out, int out_size, void* d_ws, size_t ws_size,
                              hipStream_t stream) {
  const float* x = (const float*)d_in[0];
  const float* inci = (const float*)d_in[1];
  const float* w = (const float*)d_in[2];
  const float* b = (const float*)d_in[3];
  float* out = (float*)d_out;

  size_t mBytes = (size_t)Ndim * Edim * 2;
  size_t xTBytes = (size_t)Bdim * Fdim * Edim * 2;
  if (ws_size >= mBytes + xTBytes) {
    unsigned short* m_bf = (unsigned short*)d_ws;
    unsigned short* xT = m_bf + (size_t)Ndim * Edim;
    convert_m<<<(Ndim * (size_t)Edim) / 4 / 256, 256, 0, stream>>>(w, inci, b, m_bf);
    transpose_x<<<dim3(Edim / 64, Fdim / 64, Bdim), 256, 0, stream>>>(x, xT);
    gemm8<<<256, 512, 0, stream>>>(m_bf, xT, out);
  } else {
    naive_kernel<<<Bdim * Ndim, 256, 0, stream>>>(x, inci, w, b, out);
  }
}

// Round 11
// 423.233 us; speedup vs baseline: 1.2809x; 1.2809x over previous
//
#include <hip/hip_runtime.h>
#include <hip/hip_bf16.h>

#define Ndim 4096
#define Edim 8192
#define Fdim 256
#define Bdim 16
#define EB (Edim * 2)      // bf16 row bytes = 16384
#define NT (Edim / 32)     // 256 K-tiles of BK=32

typedef __attribute__((ext_vector_type(8))) short bf16x8;
typedef __attribute__((ext_vector_type(4))) float f32x4;

__device__ __forceinline__ unsigned short f2bf(float f) {
  unsigned int u = __float_as_uint(f);
  u += 0x7fffu + ((u >> 16) & 1u);   // round-to-nearest-even
  return (unsigned short)(u >> 16);
}

__device__ __forceinline__ void gload_lds16(const void* g, void* l) {
  __builtin_amdgcn_global_load_lds(
      (const __attribute__((address_space(1))) unsigned int*)g,
      (__attribute__((address_space(3))) unsigned int*)l, 16, 0, 0);
}

// ---------------- pass 1a: m_bf16 = bf16(w*inci + b) ----------------
__global__ void convert_m(const float* __restrict__ w, const float* __restrict__ inc,
                          const float* __restrict__ bb, unsigned short* __restrict__ m) {
  size_t i = ((size_t)blockIdx.x * 256 + threadIdx.x) * 4;
  float4 wv = *(const float4*)(w + i);
  float4 iv = *(const float4*)(inc + i);
  float4 bv = *(const float4*)(bb + i);
  ushort4 o;
  o.x = f2bf(fmaf(wv.x, iv.x, bv.x));
  o.y = f2bf(fmaf(wv.y, iv.y, bv.y));
  o.z = f2bf(fmaf(wv.z, iv.z, bv.z));
  o.w = f2bf(fmaf(wv.w, iv.w, bv.w));
  *(ushort4*)(m + i) = o;
}

// ---------------- pass 1b: xT[b][f][e] = bf16(x[b][e][f]) ----------------
__global__ void transpose_x(const float* __restrict__ x, unsigned short* __restrict__ xT) {
  __shared__ unsigned short tile[64][66];
  int e0 = blockIdx.x * 64, f0 = blockIdx.y * 64, b = blockIdx.z;
  const float* xb = x + (size_t)b * Edim * Fdim;
  unsigned short* xTb = xT + (size_t)b * Fdim * Edim;
  int t = threadIdx.x;
  int fl = t & 63, rq = t >> 6;
#pragma unroll
  for (int i = 0; i < 16; i++) {
    int el = rq * 16 + i;
    float v = xb[(size_t)(e0 + el) * Fdim + f0 + fl];
    tile[el][fl] = f2bf(v);
  }
  __syncthreads();
  int ep = (t & 31) * 2;
  int fr0 = t >> 5;
#pragma unroll
  for (int j = 0; j < 8; j++) {
    int fr = fr0 + j * 8;
    unsigned int pk = (unsigned int)tile[ep][fr] | ((unsigned int)tile[ep + 1][fr] << 16);
    *(unsigned int*)&xTb[(size_t)(f0 + fr) * Edim + e0 + ep] = pk;
  }
}

// ---- BK=32, BM=128, BN=256, 8 waves, TRIPLE-buffered, 2 blocks/CU ----
// Buffer b @ smem + b*24576: A rows 0..127 @ [0,8192), B rows 0..255 @ [8192,24576).
// Row = 64 B = 4 x 16B chunks; phys chunk = logical ^ ((row>>1)&3).
// Iter t:  MFMA(frags t); vmcnt(3) [drain stage t+1; t+2 stays in flight];
//          s_barrier(t); read frags t+1 from buf[(t+1)%3]; lgkmcnt(0);
//          stage t+3 -> buf[(t+3)%3] == buf[t%3].
// WAR safety: all waves' reads of buf[t%3] (frags t) completed before their
// own lgkmcnt(0) in iter t-1, hence before barrier(t) -> stage after
// barrier(t) cannot race any read.  RAW: vmcnt(3) + barrier before reads.
__device__ __forceinline__ void stage3(const char* gA, const char* gB, char* dA) {
  gload_lds16(gA, dA);                            // A row tid>>2
  gload_lds16(gB, dA + 8192);                     // B row tid>>2
  gload_lds16(gB + (size_t)128 * EB, dA + 16384); // B row 128 + tid>>2
}

template <int VM, bool READS, bool STG>
__device__ __forceinline__ void ktile32(
    const char* bufq, const char* gA, const char* gB, char* dstq,
    const int (&offA)[4], const int (&offB)[4],
    bf16x8 (&aC)[4], bf16x8 (&bC)[4], f32x4 acc[4][4]) {
  __builtin_amdgcn_s_setprio(1);
#pragma unroll
  for (int m = 0; m < 4; ++m)
#pragma unroll
    for (int n = 0; n < 4; ++n)
      acc[m][n] = __builtin_amdgcn_mfma_f32_16x16x32_bf16(aC[m], bC[n], acc[m][n], 0, 0, 0);
  __builtin_amdgcn_s_setprio(0);
  if constexpr (VM == 3) asm volatile("s_waitcnt vmcnt(3)" ::: "memory");
  if constexpr (VM == 0) asm volatile("s_waitcnt vmcnt(0)" ::: "memory");
  __builtin_amdgcn_s_barrier();
  if constexpr (READS) {
#pragma unroll
    for (int m = 0; m < 4; ++m) aC[m] = *(const bf16x8*)(bufq + offA[m]);
#pragma unroll
    for (int n = 0; n < 4; ++n) bC[n] = *(const bf16x8*)(bufq + offB[n]);
    asm volatile("s_waitcnt lgkmcnt(0)" ::: "memory");
    if constexpr (STG) stage3(gA, gB, dstq);
  }
}

__global__ __launch_bounds__(512, 4) void gemm32(
    const unsigned short* __restrict__ A,   // [Ndim][Edim] bf16
    const unsigned short* __restrict__ Bt,  // [Bdim][Fdim][Edim] bf16
    float* __restrict__ C) {                // [Bdim][Ndim][Fdim] f32
  __shared__ __align__(16) char smem[73728];   // 3 x 24576

  const int bid = blockIdx.x;
  const int lid = ((bid & 7) << 6) | (bid >> 3);  // XCD-contiguous (512 % 8 == 0)
  const int mt = lid >> 4;   // node tile 0..31 (BM=128)
  const int bb = lid & 15;   // batch

  const int tid = threadIdx.x;
  const int lane = tid & 63;
  const int w = tid >> 6;
  const int wr = w >> 2;     // 0..1  (M: 2 x 64)
  const int wc = w & 3;      // 0..3  (N: 4 x 64)
  const int l15 = lane & 15;
  const int c = lane >> 4;   // logical 16B chunk 0..3

  // staging: thread -> (row = tid>>2, phys slot = tid&3); source chunk pre-swizzled
  const int rowS = tid >> 2;
  const int chS = (tid & 3) ^ ((rowS >> 1) & 3);
  const char* AgT = (const char*)A + (size_t)(mt * 128 + rowS) * EB + chS * 16;
  const char* BgT = (const char*)Bt + ((size_t)bb * 256 + rowS) * EB + chS * 16;

  // frag read offsets (buffer-relative), swizzled
  int offA[4], offB[4];
#pragma unroll
  for (int m = 0; m < 4; ++m) {
    int r = wr * 64 + m * 16 + l15;
    offA[m] = r * 64 + ((c ^ ((r >> 1) & 3)) << 4);
  }
#pragma unroll
  for (int n = 0; n < 4; ++n) {
    int r = wc * 64 + n * 16 + l15;
    offB[n] = 8192 + r * 64 + ((c ^ ((r >> 1) & 3)) << 4);
  }

  f32x4 acc[4][4];
#pragma unroll
  for (int m = 0; m < 4; ++m)
#pragma unroll
    for (int n = 0; n < 4; ++n) acc[m][n] = (f32x4){0.f, 0.f, 0.f, 0.f};

  // prologue: stage t0->buf0, t1->buf1, t2->buf2 (9 loads); wait t0; read t0
  stage3(AgT, BgT, smem + tid * 16);
  stage3(AgT + 64, BgT + 64, smem + 24576 + tid * 16);
  stage3(AgT + 128, BgT + 128, smem + 49152 + tid * 16);
  asm volatile("s_waitcnt vmcnt(6)" ::: "memory");
  __builtin_amdgcn_s_barrier();
  bf16x8 aC[4], bC[4];
#pragma unroll
  for (int m = 0; m < 4; ++m) aC[m] = *(const bf16x8*)(smem + offA[m]);
#pragma unroll
  for (int n = 0; n < 4; ++n) bC[n] = *(const bf16x8*)(smem + offB[n]);

  // steady: iter t = 0 .. NT-4; read buf q=(t+1)%3, stage t+3 -> buf s=t%3
  int q = 1, s = 0;
  for (int t = 0; t < NT - 3; ++t) {
    const char* bufq = smem + q * 24576;
    char* dstq = smem + s * 24576 + tid * 16;
    const size_t kb = (size_t)(t + 3) * 64;
    ktile32<3, true, true>(bufq, AgT + kb, BgT + kb, dstq, offA, offB, aC, bC, acc);
    q = (q == 2) ? 0 : q + 1;
    s = (s == 2) ? 0 : s + 1;
  }
  // t = NT-3: reads frags NT-2 from buf[(NT-2)%3 = 2]; vmcnt(3); no stage
  ktile32<3, true, false>(smem + 2 * 24576, nullptr, nullptr, nullptr, offA, offB, aC, bC, acc);
  // t = NT-2: reads frags NT-1 from buf[(NT-1)%3 = 0]; vmcnt(0); no stage
  ktile32<0, true, false>(smem, nullptr, nullptr, nullptr, offA, offB, aC, bC, acc);
  // t = NT-1: MFMA only
  ktile32<-1, false, false>(nullptr, nullptr, nullptr, nullptr, offA, offB, aC, bC, acc);

  // C write: 16x16 C/D layout col=lane&15, row=(lane>>4)*4+j
  float* Cb = C + (size_t)bb * (Ndim * Fdim) + (size_t)(mt * 128) * Fdim;
#pragma unroll
  for (int m = 0; m < 4; ++m) {
    int row0 = wr * 64 + m * 16 + ((lane >> 4) << 2);
#pragma unroll
    for (int n = 0; n < 4; ++n) {
      int col = wc * 64 + n * 16 + l15;
#pragma unroll
      for (int j = 0; j < 4; ++j)
        Cb[(size_t)(row0 + j) * Fdim + col] = acc[m][n][j];
    }
  }
}

// ---------------- fallback (ws too small): slow but correct fp32 ----------------
__global__ void naive_kernel(const float* __restrict__ x, const float* __restrict__ inci,
                             const float* __restrict__ w, const float* __restrict__ b,
                             float* __restrict__ out) {
  int n = blockIdx.x & (Ndim - 1);
  int bb = blockIdx.x >> 12;
  int f = threadIdx.x;
  const float* xb = x + (size_t)bb * Edim * Fdim;
  const size_t nE = (size_t)n * Edim;
  float acc = 0.f;
  for (int e = 0; e < Edim; e++) {
    float m = fmaf(w[nE + e], inci[nE + e], b[nE + e]);
    acc = fmaf(m, xb[(size_t)e * Fdim + f], acc);
  }
  out[(size_t)bb * Ndim * Fdim + (size_t)n * Fdim + f] = acc;
}

extern "C" void kernel_launch(void* const* d_in, const int* in_sizes, int n_in,
                              void* d_out, int out_size, void* d_ws, size_t ws_size,
                              hipStream_t stream) {
  const float* x = (const float*)d_in[0];
  const float* inci = (const float*)d_in[1];
  const float* w = (const float*)d_in[2];
  const float* b = (const float*)d_in[3];
  float* out = (float*)d_out;

  size_t mBytes = (size_t)Ndim * Edim * 2;
  size_t xTBytes = (size_t)Bdim * Fdim * Edim * 2;
  if (ws_size >= mBytes + xTBytes) {
    unsigned short* m_bf = (unsigned short*)d_ws;
    unsigned short* xT = m_bf + (size_t)Ndim * Edim;
    convert_m<<<(Ndim * (size_t)Edim) / 4 / 256, 256, 0, stream>>>(w, inci, b, m_bf);
    transpose_x<<<dim3(Edim / 64, Fdim / 64, Bdim), 256, 0, stream>>>(x, xT);
    gemm32<<<512, 512, 0, stream>>>(m_bf, xT, out);
  } else {
    naive_kernel<<<Bdim * Ndim, 256, 0, stream>>>(x, inci, w, b, out);
  }
}

// Round 12
// 329.918 us; speedup vs baseline: 1.6432x; 1.2828x over previous
//
#include <hip/hip_runtime.h>
#include <hip/hip_bf16.h>

#define Ndim 4096
#define Edim 8192
#define Fdim 256
#define Bdim 16
#define EB (Edim * 2)      // bf16 row bytes = 16384
#define NT (Edim / 64)     // 128 K-tiles of BK=64

typedef __attribute__((ext_vector_type(8))) short bf16x8;
typedef __attribute__((ext_vector_type(4))) float f32x4;

__device__ __forceinline__ unsigned short f2bf(float f) {
  unsigned int u = __float_as_uint(f);
  u += 0x7fffu + ((u >> 16) & 1u);   // round-to-nearest-even
  return (unsigned short)(u >> 16);
}

__device__ __forceinline__ void gload_lds16(const void* g, void* l) {
  __builtin_amdgcn_global_load_lds(
      (const __attribute__((address_space(1))) unsigned int*)g,
      (__attribute__((address_space(3))) unsigned int*)l, 16, 0, 0);
}

// stage one 128x64 half-matrix: 512 threads x 2 loads x 16B
__device__ __forceinline__ void stage_half(const char* g, char* d) {
  gload_lds16(g, d);
  gload_lds16(g + (size_t)64 * EB, d + 8192);
}

// swizzled LDS fragment read: logical (row r, 16B col block kk*64+khi)
#define RD(base, r, kk) \
  (*(const bf16x8*)((base) + (r) * 128 + ((((kk) * 64) + khi) ^ (((r) & 7) << 4))))

// ---------------- pass 1a: m_bf16 = bf16(w*inci + b) ----------------
__global__ void convert_m(const float* __restrict__ w, const float* __restrict__ inc,
                          const float* __restrict__ bb, unsigned short* __restrict__ m) {
  size_t i = ((size_t)blockIdx.x * 256 + threadIdx.x) * 4;
  float4 wv = *(const float4*)(w + i);
  float4 iv = *(const float4*)(inc + i);
  float4 bv = *(const float4*)(bb + i);
  ushort4 o;
  o.x = f2bf(fmaf(wv.x, iv.x, bv.x));
  o.y = f2bf(fmaf(wv.y, iv.y, bv.y));
  o.z = f2bf(fmaf(wv.z, iv.z, bv.z));
  o.w = f2bf(fmaf(wv.w, iv.w, bv.w));
  *(ushort4*)(m + i) = o;
}

// ---------------- pass 1b: xT[b][f][e] = bf16(x[b][e][f]) ----------------
__global__ void transpose_x(const float* __restrict__ x, unsigned short* __restrict__ xT) {
  __shared__ unsigned short tile[64][66];
  int e0 = blockIdx.x * 64, f0 = blockIdx.y * 64, b = blockIdx.z;
  const float* xb = x + (size_t)b * Edim * Fdim;
  unsigned short* xTb = xT + (size_t)b * Fdim * Edim;
  int t = threadIdx.x;
  int fl = t & 63, rq = t >> 6;
#pragma unroll
  for (int i = 0; i < 16; i++) {
    int el = rq * 16 + i;
    float v = xb[(size_t)(e0 + el) * Fdim + f0 + fl];
    tile[el][fl] = f2bf(v);
  }
  __syncthreads();
  int ep = (t & 31) * 2;
  int fr0 = t >> 5;
#pragma unroll
  for (int j = 0; j < 8; j++) {
    int fr = fr0 + j * 8;
    unsigned int pk = (unsigned int)tile[ep][fr] | ((unsigned int)tile[ep + 1][fr] << 16);
    *(unsigned int*)&xTb[(size_t)(f0 + fr) * Edim + e0 + ep] = pk;
  }
}

// -------- one K-tile = 4 phases; reads at prior-phase TAILS; tails 4/8/4/8 --
// P1: stage1; bar; MFMA Q00(aCur,bLoC)         tail: read bHi(4);      bar
// P2: stage2; bar; MFMA Q01(aCur,bHi)          tail: read aHi(8);      bar
// P3: stage3; bar; MFMA Q10(aHi,bLoC); vmcnt(2); tail: read next bLo(4); bar
// P4: stage4; bar; MFMA Q11(aHi,bHi)           tail: read next aLo(8); bar
// No manual lgkmcnt(0): frag loads are plain loads, compiler emits counted
// per-use lgkmcnt (finer than a full drain). vmcnt(2)@t.P3 drains t-1.S4 and
// t.S1/S2 -> tile t+1's A and B proven landed before the P3/P4 cross-buffer
// tail reads. WAR: each phase's reads complete before that wave's consuming
// MFMA (compiler wait) which precedes the phase's closing barrier; stages
// targeting a region are issued only after a barrier that post-dates all
// waves' reads of it (same map as R7, verified).
// MODE: 2 steady; 1 tile NT-2 (S1,S2 only, vmcnt(0)); 0 last (no stage/tail).
template <int MODE>
__device__ __forceinline__ void ktile(
    const char* lA, const char* lB, const char* lAn, const char* lBn,
    char* d1, const char* g1, char* d2, const char* g2,
    char* d3, const char* g3, char* d4, const char* g4,
    int lane, int wr, int wc,
    bf16x8 (&aCur)[8], bf16x8 (&bLoC)[4], f32x4 acc[8][4]) {
  const int l15 = lane & 15;
  const int khi = (lane >> 4) << 4;
  bf16x8 bHi[4], aHi[8];

  // ---- P1 ----
  if constexpr (MODE >= 1) stage_half(g1, d1);
  __builtin_amdgcn_s_barrier();
  __builtin_amdgcn_s_setprio(1);
#pragma unroll
  for (int m = 0; m < 4; ++m)
#pragma unroll
    for (int n = 0; n < 2; ++n)
#pragma unroll
      for (int kk = 0; kk < 2; ++kk)
        acc[m][n] = __builtin_amdgcn_mfma_f32_16x16x32_bf16(aCur[m * 2 + kk], bLoC[n * 2 + kk],
                                                            acc[m][n], 0, 0, 0);
  __builtin_amdgcn_s_setprio(0);
#pragma unroll
  for (int n = 0; n < 2; ++n)
#pragma unroll
    for (int kk = 0; kk < 2; ++kk)
      bHi[n * 2 + kk] = RD(lB, wc * 64 + (n + 2) * 16 + l15, kk);
  __builtin_amdgcn_s_barrier();

  // ---- P2 ----
  if constexpr (MODE >= 1) stage_half(g2, d2);
  __builtin_amdgcn_s_barrier();
  __builtin_amdgcn_s_setprio(1);
#pragma unroll
  for (int m = 0; m < 4; ++m)
#pragma unroll
    for (int n = 0; n < 2; ++n)
#pragma unroll
      for (int kk = 0; kk < 2; ++kk)
        acc[m][n + 2] = __builtin_amdgcn_mfma_f32_16x16x32_bf16(aCur[m * 2 + kk], bHi[n * 2 + kk],
                                                                acc[m][n + 2], 0, 0, 0);
  __builtin_amdgcn_s_setprio(0);
#pragma unroll
  for (int m = 0; m < 4; ++m)
#pragma unroll
    for (int kk = 0; kk < 2; ++kk)
      aHi[m * 2 + kk] = RD(lA, wr * 128 + 64 + m * 16 + l15, kk);
  __builtin_amdgcn_s_barrier();

  // ---- P3 ----
  if constexpr (MODE == 2) stage_half(g3, d3);
  __builtin_amdgcn_s_barrier();
  __builtin_amdgcn_s_setprio(1);
#pragma unroll
  for (int m = 0; m < 4; ++m)
#pragma unroll
    for (int n = 0; n < 2; ++n)
#pragma unroll
      for (int kk = 0; kk < 2; ++kk)
        acc[m + 4][n] = __builtin_amdgcn_mfma_f32_16x16x32_bf16(aHi[m * 2 + kk], bLoC[n * 2 + kk],
                                                                acc[m + 4][n], 0, 0, 0);
  __builtin_amdgcn_s_setprio(0);
  if constexpr (MODE == 2) asm volatile("s_waitcnt vmcnt(2)" ::: "memory");
  if constexpr (MODE == 1) asm volatile("s_waitcnt vmcnt(0)" ::: "memory");
  if constexpr (MODE >= 1) {
#pragma unroll
    for (int n = 0; n < 2; ++n)
#pragma unroll
      for (int kk = 0; kk < 2; ++kk)
        bLoC[n * 2 + kk] = RD(lBn, wc * 64 + n * 16 + l15, kk);
  }
  __builtin_amdgcn_s_barrier();

  // ---- P4 ----
  if constexpr (MODE == 2) stage_half(g4, d4);
  __builtin_amdgcn_s_barrier();
  __builtin_amdgcn_s_setprio(1);
#pragma unroll
  for (int m = 0; m < 4; ++m)
#pragma unroll
    for (int n = 0; n < 2; ++n)
#pragma unroll
      for (int kk = 0; kk < 2; ++kk)
        acc[m + 4][n + 2] = __builtin_amdgcn_mfma_f32_16x16x32_bf16(aHi[m * 2 + kk], bHi[n * 2 + kk],
                                                                    acc[m + 4][n + 2], 0, 0, 0);
  __builtin_amdgcn_s_setprio(0);
  if constexpr (MODE >= 1) {
#pragma unroll
    for (int m = 0; m < 4; ++m)
#pragma unroll
      for (int kk = 0; kk < 2; ++kk)
        aCur[m * 2 + kk] = RD(lAn, wr * 128 + m * 16 + l15, kk);
  }
  __builtin_amdgcn_s_barrier();
}

__global__ __launch_bounds__(512, 2) void gemm8(
    const unsigned short* __restrict__ A,   // [Ndim][Edim] bf16
    const unsigned short* __restrict__ Bt,  // [Bdim][Fdim][Edim] bf16
    float* __restrict__ C) {                // [Bdim][Ndim][Fdim] f32
  // LDS: buf0.A=0 (h1 +16384) buf0.B.h0=32768 buf0.B.h1=49152
  //      buf1.A=65536 (h1 +16384) buf1.B.h0=98304 buf1.B.h1=114688
  __shared__ __align__(16) char smem[131072];

  const int bid = blockIdx.x;
  const int lid = ((bid & 7) << 5) | (bid >> 3);  // XCD-contiguous (256 % 8 == 0)
  const int mt = lid >> 4;   // node tile 0..15
  const int bb = lid & 15;   // batch

  const int tid = threadIdx.x;
  const int lane = tid & 63;
  const int w = tid >> 6;
  const int wr = w >> 2;     // 0..1
  const int wc = w & 3;      // 0..3
  const int l15 = lane & 15;
  const int khi = (lane >> 4) << 4;

  const int r0 = tid >> 3;                         // staging row 0..63
  const int c0 = ((tid & 7) ^ (r0 & 7)) << 4;      // pre-swizzled 16B source column

  const char* Ag = (const char*)A + (size_t)(mt * 256) * EB + (size_t)r0 * EB + c0;
  const char* Bg = (const char*)Bt + (size_t)(bb * 256) * EB + (size_t)r0 * EB + c0;
  char* dst = smem + tid * 16;

  f32x4 acc[8][4];
#pragma unroll
  for (int m = 0; m < 8; ++m)
#pragma unroll
    for (int n = 0; n < 4; ++n) acc[m][n] = (f32x4){0.f, 0.f, 0.f, 0.f};

  const size_t HEB = (size_t)128 * EB;  // half-tile row offset in bytes

  // prologue: t0 full -> buf0, t1.B -> buf1.B (12 loads); wait t0 (vmcnt(4))
  stage_half(Ag, dst);
  stage_half(Ag + HEB, dst + 16384);
  stage_half(Bg, dst + 32768);
  stage_half(Bg + HEB, dst + 49152);
  stage_half(Bg + 128, dst + 98304);
  stage_half(Bg + 128 + HEB, dst + 114688);
  asm volatile("s_waitcnt vmcnt(4)" ::: "memory");
  __builtin_amdgcn_s_barrier();

  // pre-read t0's aLo + bLo (the carried P1 inputs)
  bf16x8 aCur[8];
  bf16x8 bLoC[4];
#pragma unroll
  for (int m = 0; m < 4; ++m)
#pragma unroll
    for (int kk = 0; kk < 2; ++kk)
      aCur[m * 2 + kk] = RD((const char*)smem, wr * 128 + m * 16 + l15, kk);
#pragma unroll
  for (int n = 0; n < 2; ++n)
#pragma unroll
    for (int kk = 0; kk < 2; ++kk)
      bLoC[n * 2 + kk] = RD((const char*)smem + 32768, wc * 64 + n * 16 + l15, kk);

  for (int i = 0; i < NT / 2 - 1; ++i) {
    const size_t t1b = (size_t)(2 * i + 1) * 128;
    const size_t t2b = (size_t)(2 * i + 2) * 128;
    const size_t t3b = (size_t)(2 * i + 3) * 128;
    // K-tile 2i on buf0; stages: (2i+1).A -> buf1.A, (2i+2).B -> buf0.B
    ktile<2>(smem, smem + 32768, smem + 65536, smem + 98304,
             dst + 65536, Ag + t1b,
             dst + 81920, Ag + t1b + HEB,
             dst + 32768, Bg + t2b,
             dst + 49152, Bg + t2b + HEB,
             lane, wr, wc, aCur, bLoC, acc);
    // K-tile 2i+1 on buf1; stages: (2i+2).A -> buf0.A, (2i+3).B -> buf1.B
    ktile<2>(smem + 65536, smem + 98304, smem, smem + 32768,
             dst, Ag + t2b,
             dst + 16384, Ag + t2b + HEB,
             dst + 98304, Bg + t3b,
             dst + 114688, Bg + t3b + HEB,
             lane, wr, wc, aCur, bLoC, acc);
  }
  // tail: tile NT-2 (buf0) stages (NT-1).A, vmcnt(0)@P3; tile NT-1 (buf1) bare
  {
    const size_t tlb = (size_t)(NT - 1) * 128;
    ktile<1>(smem, smem + 32768, smem + 65536, smem + 98304,
             dst + 65536, Ag + tlb,
             dst + 81920, Ag + tlb + HEB,
             nullptr, nullptr, nullptr, nullptr,
             lane, wr, wc, aCur, bLoC, acc);
    ktile<0>(smem + 65536, smem + 98304, nullptr, nullptr,
             nullptr, nullptr, nullptr, nullptr,
             nullptr, nullptr, nullptr, nullptr,
             lane, wr, wc, aCur, bLoC, acc);
  }

  float* Cb = C + (size_t)bb * (Ndim * Fdim) + (size_t)(mt * 256) * Fdim;
#pragma unroll
  for (int m = 0; m < 8; ++m) {
    int row0 = wr * 128 + m * 16 + ((lane >> 4) << 2);
#pragma unroll
    for (int n = 0; n < 4; ++n) {
      int col = wc * 64 + n * 16 + (lane & 15);
#pragma unroll
      for (int j = 0; j < 4; ++j)
        Cb[(size_t)(row0 + j) * Fdim + col] = acc[m][n][j];
    }
  }
}

// ---------------- fallback (ws too small): slow but correct fp32 ----------------
__global__ void naive_kernel(const float* __restrict__ x, const float* __restrict__ inci,
                             const float* __restrict__ w, const float* __restrict__ b,
                             float* __restrict__ out) {
  int n = blockIdx.x & (Ndim - 1);
  int bb = blockIdx.x >> 12;
  int f = threadIdx.x;
  const float* xb = x + (size_t)bb * Edim * Fdim;
  const size_t nE = (size_t)n * Edim;
  float acc = 0.f;
  for (int e = 0; e < Edim; e++) {
    float m = fmaf(w[nE + e], inci[nE + e], b[nE + e]);
    acc = fmaf(m, xb[(size_t)e * Fdim + f], acc);
  }
  out[(size_t)bb * Ndim * Fdim + (size_t)n * Fdim + f] = acc;
}

extern "C" void kernel_launch(void* const* d_in, const int* in_sizes, int n_in,
                              void* d_out, int out_size, void* d_ws, size_t ws_size,
                              hipStream_t stream) {
  const float* x = (const float*)d_in[0];
  const float* inci = (const float*)d_in[1];
  const float* w = (const float*)d_in[2];
  const float* b = (const float*)d_in[3];
  float* out = (float*)d_out;

  size_t mBytes = (size_t)Ndim * Edim * 2;
  size_t xTBytes = (size_t)Bdim * Fdim * Edim * 2;
  if (ws_size >= mBytes + xTBytes) {
    unsigned short* m_bf = (unsigned short*)d_ws;
    unsigned short* xT = m_bf + (size_t)Ndim * Edim;
    convert_m<<<(Ndim * (size_t)Edim) / 4 / 256, 256, 0, stream>>>(w, inci, b, m_bf);
    transpose_x<<<dim3(Edim / 64, Fdim / 64, Bdim), 256, 0, stream>>>(x, xT);
    gemm8<<<256, 512, 0, stream>>>(m_bf, xT, out);
  } else {
    naive_kernel<<<Bdim * Ndim, 256, 0, stream>>>(x, inci, w, b, out);
  }
}